// Round 5
// baseline (505.010 us; speedup 1.0000x reference)
//
#include <hip/hip_runtime.h>
#include <math.h>
#include <stdint.h>

// Problem constants
#define S_LEN 2048
#define HID 4096
#define NH 32
#define NKV 8
#define HD 128
#define QKV_N ((NH + 2*NKV) * HD)   // 6144
#define NQK (NH + NKV)              // 40
static __device__ __constant__ const float SCALE_F = 0.08838834764831845f; // 128^-0.5

typedef __bf16 bf16x8 __attribute__((ext_vector_type(8)));
typedef __bf16 bf16x4 __attribute__((ext_vector_type(4)));
typedef float  f32x4  __attribute__((ext_vector_type(4)));
typedef uint32_t u32x4 __attribute__((ext_vector_type(4)));

#define GLD_LDS(gptr, lptr) \
  __builtin_amdgcn_global_load_lds( \
      (const __attribute__((address_space(1))) uint32_t*)(gptr), \
      (__attribute__((address_space(3))) uint32_t*)(lptr), 16, 0, 0)

// ---------- cast fp32 -> bf16 (vectorized) ----------
__global__ void cast_bf16_kernel(const float4* __restrict__ in, __bf16* __restrict__ out, int n4) {
  int i = blockIdx.x * blockDim.x + threadIdx.x;
  if (i >= n4) return;
  float4 v = in[i];
  bf16x4 o = { (__bf16)v.x, (__bf16)v.y, (__bf16)v.z, (__bf16)v.w };
  *(bf16x4*)(out + (size_t)i * 4) = o;
}

// ---------- split-K reduction: out = a + b (f32, vectorized) ----------
__global__ void add_f32_kernel(const float4* __restrict__ a, const float4* __restrict__ b,
                               float4* __restrict__ o, int n4) {
  int i = blockIdx.x * blockDim.x + threadIdx.x;
  int stride = gridDim.x * blockDim.x;
  for (; i < n4; i += stride) {
    float4 x = a[i], y = b[i];
    float4 r; r.x = x.x + y.x; r.y = x.y + y.y; r.z = x.z + y.z; r.w = x.w + y.w;
    o[i] = r;
  }
}

// ---------- transpose + cast: in[R][C] fp32 -> out[C][R] bf16 ----------
__global__ void transpose_cast_kernel(const float* __restrict__ in, __bf16* __restrict__ out,
                                      int R, int C) {
  __shared__ float tile[32][33];
  int bx = blockIdx.x * 32;  // col of in
  int by = blockIdx.y * 32;  // row of in
  int tx = threadIdx.x, ty = threadIdx.y;
  for (int i = 0; i < 32; i += 8)
    tile[ty + i][tx] = in[(size_t)(by + ty + i) * C + bx + tx];
  __syncthreads();
  for (int i = 0; i < 32; i += 8)
    out[(size_t)(bx + ty + i) * R + by + tx] = (__bf16)tile[tx][ty + i];
}

// ---------- V transpose: Vt[kvh][d][s] = qkv[s][(NH+NKV)*HD + kvh*HD + d] ----------
__global__ void transpose_v_kernel(const __bf16* __restrict__ qkv, __bf16* __restrict__ Vt) {
  __shared__ __bf16 tile[32][33];
  int kvh = blockIdx.z;
  int sb = blockIdx.x * 32;
  int db = blockIdx.y * 32;
  int tx = threadIdx.x, ty = threadIdx.y;
  const __bf16* src = qkv + (size_t)(NH + NKV) * HD + (size_t)kvh * HD;
  for (int i = 0; i < 32; i += 8)
    tile[ty + i][tx] = src[(size_t)(sb + ty + i) * QKV_N + db + tx];
  __syncthreads();
  for (int i = 0; i < 32; i += 8)
    Vt[((size_t)kvh * HD + db + ty + i) * S_LEN + sb + tx] = tile[tx][ty + i];
}

// ---------- RoPE: split qkv -> Qr [S][NH][HD], Kr [S][NKV][HD] with rotation ----------
__global__ void rope_kernel(const __bf16* __restrict__ qkv, const int* __restrict__ pos,
                            __bf16* __restrict__ Qr, __bf16* __restrict__ Kr) {
  int idx = blockIdx.x * blockDim.x + threadIdx.x;
  int half = idx & 63;         // 0..63
  int t = idx >> 6;
  int hh = t % NQK;
  int s = t / NQK;
  if (s >= S_LEN) return;
  float p = (float)pos[s];
  float inv_freq = exp2f((float)half * -0.2076205059304601f);
  float ang = p * inv_freq;
  float cs = cosf(ang), sn = sinf(ang);
  const __bf16* src; __bf16* dst;
  if (hh < NH) {
    src = qkv + (size_t)s * QKV_N + (size_t)hh * HD;
    dst = Qr + ((size_t)s * NH + hh) * HD;
  } else {
    int kh = hh - NH;
    src = qkv + (size_t)s * QKV_N + (size_t)NH * HD + (size_t)kh * HD;
    dst = Kr + ((size_t)s * NKV + kh) * HD;
  }
  float x1 = (float)src[half], x2 = (float)src[half + 64];
  dst[half]      = (__bf16)(x1 * cs - x2 * sn);
  dst[half + 64] = (__bf16)(x2 * cs + x1 * sn);
}

// ===================================================================================
// 256x256-tile 8-phase bf16 GEMM, register-load pipelined one phase ahead (R4),
// R5: split-K support. (Kext, ld) separated: each z-slice computes C = A[:,z*Kext
// .. (z+1)*Kext) @ Bt[:, same]^T into its own output buffer (C0 / C1); a separate
// add pass reduces. Grid z=2 doubles CU coverage for the 128-tile O-proj (50%->100%).
// Hazard/overrun ledger re-checked for Kext<ld: running stage pointers overrun the
// k-slice by <=192 B into live workspace (reads only), landing in LDS buffers that
// are never consumed after the loop ends.
// ===================================================================================
template <typename OutT>
__global__ __launch_bounds__(512, 2) void gemm8p_kernel(const __bf16* __restrict__ A,
                                                        const __bf16* __restrict__ Bt,
                                                        OutT* __restrict__ C0,
                                                        OutT* __restrict__ C1,
                                                        int M, int N, int Kext, int ld) {
  __shared__ __align__(16) __bf16 sA[2][2][256 * 32];
  __shared__ __align__(16) __bf16 sB[2][2][256 * 32];
  const int tid = threadIdx.x;
  const int lane = tid & 63;
  const int wave = tid >> 6;
  const int quad = lane >> 4;
  const int l16 = lane & 15;
  const int wm = (wave >> 2) * 128;   // 2 M-warps
  const int wn = (wave & 3) * 64;     // 4 N-warps

  // split-K slice
  const int z = blockIdx.z;
  A += (size_t)z * Kext;
  Bt += (size_t)z * Kext;
  OutT* __restrict__ C = z ? C1 : C0;

  // T1 column-chunk: linear id (x fastest) -> xcd = lin&7 owns nx/8 bn-columns.
  const int nx = gridDim.x;
  size_t bm, bn;
  if (gridDim.y == 8 && (nx & 7) == 0) {
    int lin = blockIdx.y * nx + blockIdx.x;
    int j = lin >> 3, xcd = lin & 7;
    bm = (size_t)(j & 7) * 256;
    bn = (size_t)(xcd * (nx >> 3) + (j >> 3)) * 256;
  } else {
    bm = (size_t)blockIdx.y * 256;
    bn = (size_t)blockIdx.x * 256;
  }

  const int NT = Kext >> 6;           // K-tiles of 64 (even)
  const int rsw = (l16 >> 1) & 3;     // read-side chunk swizzle

  f32x4 acc[8][4] = {};
  bf16x8 aR[2][4], bR[2][4];          // double register sets (ping-pong by phase)

  // ---- per-thread global staging addresses (running pointers, +64 B per stage) ----
  const int row0 = tid >> 2;
  const int chL = (tid & 3) ^ ((tid >> 3) & 3);
  const uint64_t off128 = (uint64_t)128 * ld * 2;
  uint64_t aGA = (uint64_t)(uintptr_t)A + ((bm + row0) * (size_t)ld) * 2 + (size_t)chL * 16;
  uint64_t bGA = (uint64_t)(uintptr_t)Bt + ((bn + row0) * (size_t)ld) * 2 + (size_t)chL * 16;

  // ---- LDS byte bases ----
  typedef __attribute__((address_space(3))) __bf16 lds_bf16;
  const uint32_t sAb = (uint32_t)(uintptr_t)(lds_bf16*)&sA[0][0][0];
  const uint32_t sBb = (uint32_t)(uintptr_t)(lds_bf16*)&sB[0][0][0];
  const uint32_t wlds = (uint32_t)__builtin_amdgcn_readfirstlane(wave * 1024);
  const uint32_t aBase = sAb + (uint32_t)(((wm + l16) * 32 + (quad ^ rsw) * 8) * 2);
  const uint32_t bBase = sBb + (uint32_t)(((wn + l16) * 32 + (quad ^ rsw) * 8) * 2);
  // strides (bytes): buf 32768, khalf 16384, 16-row fragment 1024, ih 4096.

#define LDSA(bf, kk) (sAb + (bf) * 32768u + (kk) * 16384u)
#define LDSB(bf, kk) (sBb + (bf) * 32768u + (kk) * 16384u)

  // asm global_load_lds: LDS dest = m0 + lane*16 (wave-uniform base), per-lane vaddr.
#define STAGE_ASM(ga, ldsbase) \
  asm volatile("s_mov_b32 m0, %0\n\t" \
               "global_load_lds_dwordx4 %2, off\n\t" \
               "s_mov_b32 m0, %1\n\t" \
               "global_load_lds_dwordx4 %3, off" \
               :: "s"((ldsbase) + wlds), "s"((ldsbase) + wlds + 8192u), \
                  "v"(ga), "v"((ga) + off128) : "memory")

#define DSRD4(dst, baseaddr) do {                                                 \
    u32x4 t0_, t1_, t2_, t3_;                                                     \
    asm volatile("ds_read_b128 %0, %4\n\t"                                        \
                 "ds_read_b128 %1, %4 offset:1024\n\t"                            \
                 "ds_read_b128 %2, %4 offset:2048\n\t"                            \
                 "ds_read_b128 %3, %4 offset:3072"                                \
                 : "=&v"(t0_), "=&v"(t1_), "=&v"(t2_), "=&v"(t3_)                 \
                 : "v"(baseaddr));                                                \
    dst[0] = __builtin_bit_cast(bf16x8, t0_);                                     \
    dst[1] = __builtin_bit_cast(bf16x8, t1_);                                     \
    dst[2] = __builtin_bit_cast(bf16x8, t2_);                                     \
    dst[3] = __builtin_bit_cast(bf16x8, t3_);                                     \
  } while (0)

#define ISSUE_A(set, bf, kk, ih) DSRD4(aR[set], aBase + (bf) * 32768u + (kk) * 16384u + (ih) * 4096u)
#define ISSUE_B(set, bf, kk)     DSRD4(bR[set], bBase + (bf) * 32768u + (kk) * 16384u)

#define MFMA16(as, bs, ih) do {                                                   \
    __builtin_amdgcn_s_setprio(1);                                                \
    _Pragma("unroll")                                                             \
    for (int i_ = 0; i_ < 4; ++i_)                                                \
      _Pragma("unroll")                                                           \
      for (int j_ = 0; j_ < 4; ++j_)                                              \
        acc[(ih) * 4 + i_][j_] = __builtin_amdgcn_mfma_f32_16x16x32_bf16(         \
            aR[as][i_], bR[bs][j_], acc[(ih) * 4 + i_][j_], 0, 0, 0);             \
    __builtin_amdgcn_s_setprio(0);                                                \
    __builtin_amdgcn_sched_barrier(0);                                            \
  } while (0)

#define BAR() __builtin_amdgcn_s_barrier()
#define LGKM4() do { asm volatile("s_waitcnt lgkmcnt(4)");                        \
                     __builtin_amdgcn_sched_barrier(0); } while (0)
#define LGKM8() do { asm volatile("s_waitcnt lgkmcnt(8)");                        \
                     __builtin_amdgcn_sched_barrier(0); } while (0)
#define VMCNT4() do { asm volatile("s_waitcnt vmcnt(4)");                         \
                      __builtin_amdgcn_sched_barrier(0); } while (0)

  // ---- prologue: tile0 (4 halves) + tile1 k0; drain tile0; publish; reads for p0 ----
  STAGE_ASM(aGA,        LDSA(0, 0));
  STAGE_ASM(bGA,        LDSB(0, 0));
  STAGE_ASM(aGA + 64,   LDSA(0, 1));
  STAGE_ASM(bGA + 64,   LDSB(0, 1));
  STAGE_ASM(aGA + 128,  LDSA(1, 0));
  STAGE_ASM(bGA + 128,  LDSB(1, 0));
  aGA += 192; bGA += 192;
  asm volatile("s_waitcnt vmcnt(8)");
  __builtin_amdgcn_sched_barrier(0);
  BAR();
  ISSUE_A(0, 0, 0, 0); ISSUE_B(0, 0, 0);   // operands for p0 (8 reads in flight)

  for (int u = 0; u < (NT >> 1); ++u) {
    // ---- p0: MFMA(buf0,kk0,ih0); issue A(buf0,kk0,ih1); stage sA[1][1] ----
    VMCNT4();
    ISSUE_A(1, 0, 0, 1);
    BAR();
    LGKM4();
    MFMA16(0, 0, 0);
    STAGE_ASM(aGA, LDSA(1, 1)); aGA += 64;
    // ---- p1: MFMA(ih1); issue A+B(buf0,kk1); stage sB[1][1] ----
    ISSUE_A(0, 0, 1, 0); ISSUE_B(1, 0, 1);
    BAR();
    LGKM8();
    MFMA16(1, 0, 1);
    STAGE_ASM(bGA, LDSB(1, 1)); bGA += 64;
    // ---- p2 ----
    VMCNT4();
    ISSUE_A(1, 0, 1, 1);
    BAR();
    LGKM4();
    MFMA16(0, 1, 0);
    STAGE_ASM(aGA, LDSA(0, 0)); aGA += 64;
    // ---- p3 ----
    ISSUE_A(0, 1, 0, 0); ISSUE_B(0, 1, 0);
    BAR();
    LGKM8();
    MFMA16(1, 1, 1);
    STAGE_ASM(bGA, LDSB(0, 0)); bGA += 64;
    // ---- p4 ----
    VMCNT4();
    ISSUE_A(1, 1, 0, 1);
    BAR();
    LGKM4();
    MFMA16(0, 0, 0);
    STAGE_ASM(aGA, LDSA(0, 1)); aGA += 64;
    // ---- p5 ----
    ISSUE_A(0, 1, 1, 0); ISSUE_B(1, 1, 1);
    BAR();
    LGKM8();
    MFMA16(1, 0, 1);
    STAGE_ASM(bGA, LDSB(0, 1)); bGA += 64;
    // ---- p6 ----
    VMCNT4();
    ISSUE_A(1, 1, 1, 1);
    BAR();
    LGKM4();
    MFMA16(0, 1, 0);
    STAGE_ASM(aGA, LDSA(1, 0)); aGA += 64;
    // ---- p7 ----
    ISSUE_A(0, 0, 0, 0); ISSUE_B(0, 0, 0);
    BAR();
    LGKM8();
    MFMA16(1, 1, 1);
    STAGE_ASM(bGA, LDSB(1, 0)); bGA += 64;
  }
  // tail stages overrun the k-slice by <=192 B (reads into live workspace only)
  // and fill LDS buffers that are never consumed after the loop.

  asm volatile("s_waitcnt vmcnt(0) lgkmcnt(0)");
  __builtin_amdgcn_sched_barrier(0);

  #pragma unroll
  for (int i = 0; i < 8; ++i)
    #pragma unroll
    for (int j = 0; j < 4; ++j)
      #pragma unroll
      for (int r = 0; r < 4; ++r) {
        size_t row = bm + wm + i * 16 + quad * 4 + r;
        size_t col = bn + wn + j * 16 + l16;
        C[row * (size_t)N + col] = (OutT)acc[i][j][r];
      }

#undef LDSA
#undef LDSB
#undef STAGE_ASM
#undef DSRD4
#undef ISSUE_A
#undef ISSUE_B
#undef MFMA16
#undef BAR
#undef LGKM4
#undef LGKM8
#undef VMCNT4
}

// ---------- flash attention v3 (causal, GQA) — 2-phase pipelined staging ----------
// (unchanged from R2)
__global__ __launch_bounds__(256, 2) void attn_kernel(const __bf16* __restrict__ Qr,
                                                      const __bf16* __restrict__ Kr,
                                                      const __bf16* __restrict__ Vt,
                                                      __bf16* __restrict__ O) {
  __shared__ __align__(16) char smem[73728];
  __bf16* Ps = (__bf16*)(smem + 65536);    // [4 wave][16 q][64 key], swizzled

  const int bid = blockIdx.x;
  const int h = bid & (NH - 1);
  const int qb = (S_LEN / 64 - 1) - (bid >> 5);     // longest first
  const int kvh = h >> 2;                            // REP = 4
  const int tid = threadIdx.x;
  const int lane = tid & 63, wave = tid >> 6;
  const int quad = lane >> 4, l16 = lane & 15;
  const int sw = l16 & 7;                            // swizzle key
  const int q0 = qb * 64;

#define STAGE_KV(kbase, bufv) do {                                                 \
    char* kd_ = smem + (bufv) * 16384;                                             \
    char* vd_ = smem + 32768 + (bufv) * 16384;                                     \
    _Pragma("unroll")                                                              \
    for (int pass_ = 0; pass_ < 4; ++pass_) {                                      \
      int c_ = pass_ * 256 + tid;                                                  \
      int row_ = c_ >> 4, ch_ = c_ & 15;                                           \
      int chs_ = ch_ ^ (row_ & 7);                                                 \
      GLD_LDS(&Kr[(size_t)((kbase) + row_) * (NKV * HD) + (size_t)kvh * HD + chs_ * 8], \
              kd_ + c_ * 16);                                                      \
    }                                                                              \
    _Pragma("unroll")                                                              \
    for (int pass_ = 0; pass_ < 4; ++pass_) {                                      \
      int c_ = pass_ * 256 + tid;                                                  \
      int d_ = c_ >> 3, ch_ = c_ & 7;                                              \
      int chs_ = ch_ ^ (d_ & 7);                                                   \
      GLD_LDS(&Vt[((size_t)kvh * HD + d_) * S_LEN + (kbase) + chs_ * 8],           \
              vd_ + c_ * 16);                                                      \
    }                                                                              \
  } while (0)

  bf16x8 qf[4];
  {
    const __bf16* qp = Qr + (size_t)(q0 + wave * 16 + l16) * (NH * HD) + (size_t)h * HD + quad * 8;
    for (int kk = 0; kk < 4; ++kk) qf[kk] = *(const bf16x8*)(qp + kk * 32);
  }
  f32x4 oacc[8] = {};
  float m2 = -INFINITY, l_i = 0.0f;
  const float C2 = SCALE_F * 1.4426950408889634f;

  int buf = 0;
  STAGE_KV(0, 0);
  for (int kb = 0; kb <= q0; kb += 64) {
    __syncthreads();
    if (kb + 64 <= q0) STAGE_KV(kb + 64, buf ^ 1);

    const __bf16* Ks = (const __bf16*)(smem + buf * 16384);
    const __bf16* Vs = (const __bf16*)(smem + 32768 + buf * 16384);

    f32x4 sc[4] = {};
    __builtin_amdgcn_s_setprio(1);
    for (int jt = 0; jt < 4; ++jt)
      for (int kk = 0; kk < 4; ++kk) {
        bf16x8 kf = *(const bf16x8*)&Ks[(jt * 16 + l16) * 128 + ((kk * 4 + quad) ^ sw) * 8];
        sc[jt] = __builtin_amdgcn_mfma_f32_16x16x32_bf16(kf, qf[kk], sc[jt], 0, 0, 0);
      }
    __builtin_amdgcn_s_setprio(0);

    float s[16];
    for (int jt = 0; jt < 4; ++jt)
      for (int r = 0; r < 4; ++r) s[jt * 4 + r] = sc[jt][r];
    if (kb == q0) {
      int qloc = wave * 16 + l16;
      for (int jt = 0; jt < 4; ++jt)
        for (int r = 0; r < 4; ++r)
          if (jt * 16 + quad * 4 + r > qloc) s[jt * 4 + r] = -INFINITY;
    }
    float mx = s[0];
    for (int i = 1; i < 16; ++i) mx = fmaxf(mx, s[i]);
    mx = fmaxf(mx, __shfl_xor(mx, 16, 64));
    mx = fmaxf(mx, __shfl_xor(mx, 32, 64));
    float m2new = fmaxf(m2, mx * C2);
    float alpha = exp2f(m2 - m2new);
    float pv[16], sum = 0.0f;
    for (int i = 0; i < 16; ++i) { pv[i] = exp2f(fmaf(s[i], C2, -m2new)); sum += pv[i]; }
    sum += __shfl_xor(sum, 16, 64);
    sum += __shfl_xor(sum, 32, 64);
    l_i = l_i * alpha + sum;
    m2 = m2new;
    for (int dt = 0; dt < 8; ++dt) oacc[dt] *= alpha;

    __bf16* pw = Ps + wave * 1024 + l16 * 64;
    for (int jt = 0; jt < 4; ++jt) {
      bf16x4 pk = { (__bf16)pv[jt*4+0], (__bf16)pv[jt*4+1], (__bf16)pv[jt*4+2], (__bf16)pv[jt*4+3] };
      int chunk = jt * 2 + (quad >> 1);
      *(bf16x4*)&pw[((chunk ^ sw) * 8) + (quad & 1) * 4] = pk;
    }
    __builtin_amdgcn_s_setprio(1);
    for (int half = 0; half < 2; ++half) {
      bf16x8 pf = *(const bf16x8*)&pw[((half * 4 + quad) ^ sw) * 8];
      for (int dt = 0; dt < 8; ++dt) {
        bf16x8 vf = *(const bf16x8*)&Vs[(dt * 16 + l16) * 64 + ((half * 4 + quad) ^ sw) * 8];
        oacc[dt] = __builtin_amdgcn_mfma_f32_16x16x32_bf16(vf, pf, oacc[dt], 0, 0, 0);
      }
    }
    __builtin_amdgcn_s_setprio(0);
    buf ^= 1;
  }
  __syncthreads();

#undef STAGE_KV

  float* scr = (float*)smem + wave * 2112;
  float inv = 1.0f / l_i;
  for (int dt = 0; dt < 8; ++dt) {
    f32x4 v = oacc[dt] * inv;
    *(f32x4*)&scr[l16 * 132 + dt * 16 + quad * 4] = v;
  }
  for (int it = 0; it < 4; ++it) {
    int c = it * 64 + lane;
    int row = c >> 4, ch = c & 15;
    const float* sp = &scr[row * 132 + ch * 8];
    f32x4 a = *(const f32x4*)sp;
    f32x4 b = *(const f32x4*)(sp + 4);
    bf16x8 o = { (__bf16)a[0], (__bf16)a[1], (__bf16)a[2], (__bf16)a[3],
                 (__bf16)b[0], (__bf16)b[1], (__bf16)b[2], (__bf16)b[3] };
    *(bf16x8*)&O[(size_t)(q0 + wave * 16 + row) * (NH * HD) + (size_t)h * HD + ch * 8] = o;
  }
}

extern "C" void kernel_launch(void* const* d_in, const int* in_sizes, int n_in,
                              void* d_out, int out_size, void* d_ws, size_t ws_size,
                              hipStream_t stream) {
  const float* hidden    = (const float*)d_in[0];
  const int*   positions = (const int*)d_in[1];
  const float* Wqkv      = (const float*)d_in[2];
  const float* Wo        = (const float*)d_in[3];
  float* out = (float*)d_out;

  char* p = (char*)d_ws;
  auto alloc = [&](size_t bytes) { char* r = p; p += (bytes + 255) & ~(size_t)255; return r; };
  __bf16* hid_bf = (__bf16*)alloc((size_t)S_LEN * HID * 2);       // 16 MB (reused as attn_out)
  __bf16* wqkvT  = (__bf16*)alloc((size_t)QKV_N * HID * 2);       // 48 MB  [6144][4096]
  __bf16* woT    = (__bf16*)alloc((size_t)HID * HID * 2);         // 32 MB  [4096][4096]
  __bf16* qkv    = (__bf16*)alloc((size_t)S_LEN * QKV_N * 2);     // 24 MB
  __bf16* Qr     = (__bf16*)alloc((size_t)S_LEN * NH * HD * 2);   // 16 MB
  __bf16* Kr     = (__bf16*)alloc((size_t)S_LEN * NKV * HD * 2);  // 4 MB
  __bf16* Vt     = (__bf16*)alloc((size_t)S_LEN * NKV * HD * 2);  // 4 MB
  __bf16* attn   = hid_bf;  // hidden_bf16 dead after GEMM1

  // split-K partial buffers for O-proj, overlaid on DEAD regions:
  //   Cp0 = wqkvT (48 MB >= 32 MB; dead after QKV GEMM)
  //   Cp1 = qkv..Qr (24+16 = 40 MB contiguous >= 32 MB; dead after attn)
  float* Cp0 = (float*)wqkvT;
  float* Cp1 = (float*)qkv;

  {
    int n4 = S_LEN * HID / 4;
    cast_bf16_kernel<<<(n4 + 255) / 256, 256, 0, stream>>>((const float4*)hidden, hid_bf, n4);
  }
  transpose_cast_kernel<<<dim3(QKV_N / 32, HID / 32), dim3(32, 8), 0, stream>>>(Wqkv, wqkvT, HID, QKV_N);
  transpose_cast_kernel<<<dim3(HID / 32, HID / 32), dim3(32, 8), 0, stream>>>(Wo, woT, HID, HID);
  gemm8p_kernel<__bf16><<<dim3(QKV_N / 256, S_LEN / 256, 1), 512, 0, stream>>>(
      hid_bf, wqkvT, qkv, qkv, S_LEN, QKV_N, HID, HID);
  {
    int total = S_LEN * NQK * 64;
    rope_kernel<<<total / 256, 256, 0, stream>>>(qkv, positions, Qr, Kr);
  }
  transpose_v_kernel<<<dim3(S_LEN / 32, HD / 32, NKV), dim3(32, 8), 0, stream>>>(qkv, Vt);
  attn_kernel<<<NH * (S_LEN / 64), 256, 0, stream>>>(Qr, Kr, Vt, attn);
  // O-proj: split-K x2 -> 256 blocks (full CU coverage), then reduce.
  gemm8p_kernel<float><<<dim3(HID / 256, S_LEN / 256, 2), 512, 0, stream>>>(
      attn, woT, Cp0, Cp1, S_LEN, HID, HID / 2, HID);
  {
    int n4 = S_LEN * HID / 4;
    add_f32_kernel<<<2048, 256, 0, stream>>>((const float4*)Cp0, (const float4*)Cp1,
                                             (float4*)out, n4);
  }
}

// Round 6
// 483.851 us; speedup vs baseline: 1.0437x; 1.0437x over previous
//
#include <hip/hip_runtime.h>
#include <math.h>
#include <stdint.h>

// Problem constants
#define S_LEN 2048
#define HID 4096
#define NH 32
#define NKV 8
#define HD 128
#define QKV_N ((NH + 2*NKV) * HD)   // 6144
#define NQK (NH + NKV)              // 40
static __device__ __constant__ const float SCALE_F = 0.08838834764831845f; // 128^-0.5

typedef __bf16 bf16x8 __attribute__((ext_vector_type(8)));
typedef __bf16 bf16x4 __attribute__((ext_vector_type(4)));
typedef float  f32x4  __attribute__((ext_vector_type(4)));
typedef uint32_t u32x4 __attribute__((ext_vector_type(4)));

#define GLD_LDS(gptr, lptr) \
  __builtin_amdgcn_global_load_lds( \
      (const __attribute__((address_space(1))) uint32_t*)(gptr), \
      (__attribute__((address_space(3))) uint32_t*)(lptr), 16, 0, 0)

// ---------- 64x64 transpose+cast tile helper: out[c][r] = (bf16)in[r][c] ----------
// float4 coalesced loads (256B/row), bf16x2 stores (128B/wave), [64][65] LDS
// (2-way read aliasing = free per m136).
__device__ __forceinline__ void tp64(const float* __restrict__ in, __bf16* __restrict__ out,
                                     int R, int C, int bx, int by, int tid, float* tile) {
  int lr = tid >> 4;           // 0..15
  int lc = (tid & 15) * 4;     // 0..60
  #pragma unroll
  for (int p = 0; p < 4; ++p) {
    int r = p * 16 + lr;
    const float4 v = *(const float4*)&in[(size_t)(by + r) * C + bx + lc];
    float* t = &tile[r * 65 + lc];
    t[0] = v.x; t[1] = v.y; t[2] = v.z; t[3] = v.w;
  }
  __syncthreads();
  int oc = tid >> 5;           // 0..7
  int orr = (tid & 31) * 2;
  #pragma unroll
  for (int p = 0; p < 8; ++p) {
    int c = p * 8 + oc;
    float v0 = tile[orr * 65 + c];
    float v1 = tile[(orr + 1) * 65 + c];
    __bf16 b2[2] = { (__bf16)v0, (__bf16)v1 };
    *(uint32_t*)&out[(size_t)(bx + c) * R + by + orr] = *(uint32_t*)b2;
  }
}

// ---------- fused prep: cast hidden -> bf16 | transpose Wqkv | transpose Wo ----------
// blockIdx.x: [0,2048) cast ; [2048,8192) Wqkv tp (96x64 tiles) ; [8192,12288) Wo tp.
__global__ __launch_bounds__(256) void fused_prep_kernel(const float* __restrict__ hidden,
                                                         __bf16* __restrict__ hid_bf,
                                                         const float* __restrict__ Wqkv,
                                                         __bf16* __restrict__ wqkvT,
                                                         const float* __restrict__ Wo,
                                                         __bf16* __restrict__ woT) {
  __shared__ float tile[64 * 65];
  const int b = blockIdx.x;
  const int tid = threadIdx.x;
  if (b < 2048) {
    // cast: 2048*4096 f32 = 2,097,152 float4; 524,288 threads x 4 each
    const float4* in4 = (const float4*)hidden;
    int i = b * 256 + tid;
    #pragma unroll
    for (int k = 0; k < 4; ++k) {
      float4 v = in4[i + k * 524288];
      bf16x4 o = { (__bf16)v.x, (__bf16)v.y, (__bf16)v.z, (__bf16)v.w };
      *(bf16x4*)(hid_bf + (size_t)(i + k * 524288) * 4) = o;
    }
  } else if (b < 8192) {
    int id = b - 2048;                 // 96 x 64 tiles
    int bx = (id % 96) * 64, by = (id / 96) * 64;
    tp64(Wqkv, wqkvT, HID, QKV_N, bx, by, tid, tile);
  } else {
    int id = b - 8192;                 // 64 x 64 tiles
    int bx = (id & 63) * 64, by = (id >> 6) * 64;
    tp64(Wo, woT, HID, HID, bx, by, tid, tile);
  }
}

// ---------- fused rope + V-transpose ----------
// blockIdx.x: [0,20480) rope ; [20480,22528) tpv (64 x 4 x 8 tiles of 32x32).
__global__ __launch_bounds__(256) void fused_rope_tpv_kernel(const __bf16* __restrict__ qkv,
                                                             const int* __restrict__ pos,
                                                             __bf16* __restrict__ Qr,
                                                             __bf16* __restrict__ Kr,
                                                             __bf16* __restrict__ Vt) {
  __shared__ __bf16 tile[32][33];
  const int b = blockIdx.x;
  const int tid = threadIdx.x;
  if (b < 20480) {
    int idx = b * 256 + tid;
    int half = idx & 63;
    int t = idx >> 6;
    int hh = t % NQK;
    int s = t / NQK;
    if (s >= S_LEN) return;
    float p = (float)pos[s];
    float inv_freq = exp2f((float)half * -0.2076205059304601f);
    float ang = p * inv_freq;
    float cs = cosf(ang), sn = sinf(ang);
    const __bf16* src; __bf16* dst;
    if (hh < NH) {
      src = qkv + (size_t)s * QKV_N + (size_t)hh * HD;
      dst = Qr + ((size_t)s * NH + hh) * HD;
    } else {
      int kh = hh - NH;
      src = qkv + (size_t)s * QKV_N + (size_t)NH * HD + (size_t)kh * HD;
      dst = Kr + ((size_t)s * NKV + kh) * HD;
    }
    float x1 = (float)src[half], x2 = (float)src[half + 64];
    dst[half]      = (__bf16)(x1 * cs - x2 * sn);
    dst[half + 64] = (__bf16)(x2 * cs + x1 * sn);
  } else {
    int id = b - 20480;
    int sb = (id & 63) * 32;
    int db = ((id >> 6) & 3) * 32;
    int kvh = id >> 8;
    int tx = tid & 31, ty = tid >> 5;
    const __bf16* src = qkv + (size_t)(NH + NKV) * HD + (size_t)kvh * HD;
    for (int i = 0; i < 32; i += 8)
      tile[ty + i][tx] = src[(size_t)(sb + ty + i) * QKV_N + db + tx];
    __syncthreads();
    for (int i = 0; i < 32; i += 8)
      Vt[((size_t)kvh * HD + db + ty + i) * S_LEN + sb + tx] = tile[tx][ty + i];
  }
}

// ===================================================================================
// 256x256-tile 8-phase bf16 GEMM, register-load pipelined one phase ahead (R4).
// (Split-K plumbing retained but launched with z=1 after R5's measured regression.)
// ===================================================================================
template <typename OutT>
__global__ __launch_bounds__(512, 2) void gemm8p_kernel(const __bf16* __restrict__ A,
                                                        const __bf16* __restrict__ Bt,
                                                        OutT* __restrict__ C0,
                                                        OutT* __restrict__ C1,
                                                        int M, int N, int Kext, int ld) {
  __shared__ __align__(16) __bf16 sA[2][2][256 * 32];
  __shared__ __align__(16) __bf16 sB[2][2][256 * 32];
  const int tid = threadIdx.x;
  const int lane = tid & 63;
  const int wave = tid >> 6;
  const int quad = lane >> 4;
  const int l16 = lane & 15;
  const int wm = (wave >> 2) * 128;   // 2 M-warps
  const int wn = (wave & 3) * 64;     // 4 N-warps

  // split-K slice
  const int z = blockIdx.z;
  A += (size_t)z * Kext;
  Bt += (size_t)z * Kext;
  OutT* __restrict__ C = z ? C1 : C0;

  // T1 column-chunk: linear id (x fastest) -> xcd = lin&7 owns nx/8 bn-columns.
  const int nx = gridDim.x;
  size_t bm, bn;
  if (gridDim.y == 8 && (nx & 7) == 0) {
    int lin = blockIdx.y * nx + blockIdx.x;
    int j = lin >> 3, xcd = lin & 7;
    bm = (size_t)(j & 7) * 256;
    bn = (size_t)(xcd * (nx >> 3) + (j >> 3)) * 256;
  } else {
    bm = (size_t)blockIdx.y * 256;
    bn = (size_t)blockIdx.x * 256;
  }

  const int NT = Kext >> 6;           // K-tiles of 64 (even)
  const int rsw = (l16 >> 1) & 3;     // read-side chunk swizzle

  f32x4 acc[8][4] = {};
  bf16x8 aR[2][4], bR[2][4];          // double register sets (ping-pong by phase)

  // ---- per-thread global staging addresses (running pointers, +64 B per stage) ----
  const int row0 = tid >> 2;
  const int chL = (tid & 3) ^ ((tid >> 3) & 3);
  const uint64_t off128 = (uint64_t)128 * ld * 2;
  uint64_t aGA = (uint64_t)(uintptr_t)A + ((bm + row0) * (size_t)ld) * 2 + (size_t)chL * 16;
  uint64_t bGA = (uint64_t)(uintptr_t)Bt + ((bn + row0) * (size_t)ld) * 2 + (size_t)chL * 16;

  // ---- LDS byte bases ----
  typedef __attribute__((address_space(3))) __bf16 lds_bf16;
  const uint32_t sAb = (uint32_t)(uintptr_t)(lds_bf16*)&sA[0][0][0];
  const uint32_t sBb = (uint32_t)(uintptr_t)(lds_bf16*)&sB[0][0][0];
  const uint32_t wlds = (uint32_t)__builtin_amdgcn_readfirstlane(wave * 1024);
  const uint32_t aBase = sAb + (uint32_t)(((wm + l16) * 32 + (quad ^ rsw) * 8) * 2);
  const uint32_t bBase = sBb + (uint32_t)(((wn + l16) * 32 + (quad ^ rsw) * 8) * 2);
  // strides (bytes): buf 32768, khalf 16384, 16-row fragment 1024, ih 4096.

#define LDSA(bf, kk) (sAb + (bf) * 32768u + (kk) * 16384u)
#define LDSB(bf, kk) (sBb + (bf) * 32768u + (kk) * 16384u)

#define STAGE_ASM(ga, ldsbase) \
  asm volatile("s_mov_b32 m0, %0\n\t" \
               "global_load_lds_dwordx4 %2, off\n\t" \
               "s_mov_b32 m0, %1\n\t" \
               "global_load_lds_dwordx4 %3, off" \
               :: "s"((ldsbase) + wlds), "s"((ldsbase) + wlds + 8192u), \
                  "v"(ga), "v"((ga) + off128) : "memory")

#define DSRD4(dst, baseaddr) do {                                                 \
    u32x4 t0_, t1_, t2_, t3_;                                                     \
    asm volatile("ds_read_b128 %0, %4\n\t"                                        \
                 "ds_read_b128 %1, %4 offset:1024\n\t"                            \
                 "ds_read_b128 %2, %4 offset:2048\n\t"                            \
                 "ds_read_b128 %3, %4 offset:3072"                                \
                 : "=&v"(t0_), "=&v"(t1_), "=&v"(t2_), "=&v"(t3_)                 \
                 : "v"(baseaddr));                                                \
    dst[0] = __builtin_bit_cast(bf16x8, t0_);                                     \
    dst[1] = __builtin_bit_cast(bf16x8, t1_);                                     \
    dst[2] = __builtin_bit_cast(bf16x8, t2_);                                     \
    dst[3] = __builtin_bit_cast(bf16x8, t3_);                                     \
  } while (0)

#define ISSUE_A(set, bf, kk, ih) DSRD4(aR[set], aBase + (bf) * 32768u + (kk) * 16384u + (ih) * 4096u)
#define ISSUE_B(set, bf, kk)     DSRD4(bR[set], bBase + (bf) * 32768u + (kk) * 16384u)

#define MFMA16(as, bs, ih) do {                                                   \
    __builtin_amdgcn_s_setprio(1);                                                \
    _Pragma("unroll")                                                             \
    for (int i_ = 0; i_ < 4; ++i_)                                                \
      _Pragma("unroll")                                                           \
      for (int j_ = 0; j_ < 4; ++j_)                                              \
        acc[(ih) * 4 + i_][j_] = __builtin_amdgcn_mfma_f32_16x16x32_bf16(         \
            aR[as][i_], bR[bs][j_], acc[(ih) * 4 + i_][j_], 0, 0, 0);             \
    __builtin_amdgcn_s_setprio(0);                                                \
    __builtin_amdgcn_sched_barrier(0);                                            \
  } while (0)

#define BAR() __builtin_amdgcn_s_barrier()
#define LGKM4() do { asm volatile("s_waitcnt lgkmcnt(4)");                        \
                     __builtin_amdgcn_sched_barrier(0); } while (0)
#define LGKM8() do { asm volatile("s_waitcnt lgkmcnt(8)");                        \
                     __builtin_amdgcn_sched_barrier(0); } while (0)
#define VMCNT4() do { asm volatile("s_waitcnt vmcnt(4)");                         \
                      __builtin_amdgcn_sched_barrier(0); } while (0)

  // ---- prologue: tile0 (4 halves) + tile1 k0; drain tile0; publish; reads for p0 ----
  STAGE_ASM(aGA,        LDSA(0, 0));
  STAGE_ASM(bGA,        LDSB(0, 0));
  STAGE_ASM(aGA + 64,   LDSA(0, 1));
  STAGE_ASM(bGA + 64,   LDSB(0, 1));
  STAGE_ASM(aGA + 128,  LDSA(1, 0));
  STAGE_ASM(bGA + 128,  LDSB(1, 0));
  aGA += 192; bGA += 192;
  asm volatile("s_waitcnt vmcnt(8)");
  __builtin_amdgcn_sched_barrier(0);
  BAR();
  ISSUE_A(0, 0, 0, 0); ISSUE_B(0, 0, 0);   // operands for p0 (8 reads in flight)

  for (int u = 0; u < (NT >> 1); ++u) {
    // ---- p0 ----
    VMCNT4();
    ISSUE_A(1, 0, 0, 1);
    BAR();
    LGKM4();
    MFMA16(0, 0, 0);
    STAGE_ASM(aGA, LDSA(1, 1)); aGA += 64;
    // ---- p1 ----
    ISSUE_A(0, 0, 1, 0); ISSUE_B(1, 0, 1);
    BAR();
    LGKM8();
    MFMA16(1, 0, 1);
    STAGE_ASM(bGA, LDSB(1, 1)); bGA += 64;
    // ---- p2 ----
    VMCNT4();
    ISSUE_A(1, 0, 1, 1);
    BAR();
    LGKM4();
    MFMA16(0, 1, 0);
    STAGE_ASM(aGA, LDSA(0, 0)); aGA += 64;
    // ---- p3 ----
    ISSUE_A(0, 1, 0, 0); ISSUE_B(0, 1, 0);
    BAR();
    LGKM8();
    MFMA16(1, 1, 1);
    STAGE_ASM(bGA, LDSB(0, 0)); bGA += 64;
    // ---- p4 ----
    VMCNT4();
    ISSUE_A(1, 1, 0, 1);
    BAR();
    LGKM4();
    MFMA16(0, 0, 0);
    STAGE_ASM(aGA, LDSA(0, 1)); aGA += 64;
    // ---- p5 ----
    ISSUE_A(0, 1, 1, 0); ISSUE_B(1, 1, 1);
    BAR();
    LGKM8();
    MFMA16(1, 0, 1);
    STAGE_ASM(bGA, LDSB(0, 1)); bGA += 64;
    // ---- p6 ----
    VMCNT4();
    ISSUE_A(1, 1, 1, 1);
    BAR();
    LGKM4();
    MFMA16(0, 1, 0);
    STAGE_ASM(aGA, LDSA(1, 0)); aGA += 64;
    // ---- p7 ----
    ISSUE_A(0, 0, 0, 0); ISSUE_B(0, 0, 0);
    BAR();
    LGKM8();
    MFMA16(1, 1, 1);
    STAGE_ASM(bGA, LDSB(1, 0)); bGA += 64;
  }
  // tail stages overrun the k-slice by <=192 B (reads into live workspace only)
  // and fill LDS buffers that are never consumed after the loop.

  asm volatile("s_waitcnt vmcnt(0) lgkmcnt(0)");
  __builtin_amdgcn_sched_barrier(0);

  #pragma unroll
  for (int i = 0; i < 8; ++i)
    #pragma unroll
    for (int j = 0; j < 4; ++j)
      #pragma unroll
      for (int r = 0; r < 4; ++r) {
        size_t row = bm + wm + i * 16 + quad * 4 + r;
        size_t col = bn + wn + j * 16 + l16;
        C[row * (size_t)N + col] = (OutT)acc[i][j][r];
      }

#undef LDSA
#undef LDSB
#undef STAGE_ASM
#undef DSRD4
#undef ISSUE_A
#undef ISSUE_B
#undef MFMA16
#undef BAR
#undef LGKM4
#undef LGKM8
#undef VMCNT4
}

// ---------- flash attention v3 (causal, GQA) — 2-phase pipelined staging ----------
// R6: T13 defer-max. Skip the O/l rescale when __all(mx*C2 <= m2 + 11.54)
// (= HK's e^8 bound in log2 domain; P bounded by 2^11.54 ~ 2980, fits bf16).
// First tile: m2 = -INF forces the rescale path (exact). Branch is wave-uniform.
__global__ __launch_bounds__(256, 2) void attn_kernel(const __bf16* __restrict__ Qr,
                                                      const __bf16* __restrict__ Kr,
                                                      const __bf16* __restrict__ Vt,
                                                      __bf16* __restrict__ O) {
  __shared__ __align__(16) char smem[73728];
  __bf16* Ps = (__bf16*)(smem + 65536);    // [4 wave][16 q][64 key], swizzled

  const int bid = blockIdx.x;
  const int h = bid & (NH - 1);
  const int qb = (S_LEN / 64 - 1) - (bid >> 5);     // longest first
  const int kvh = h >> 2;                            // REP = 4
  const int tid = threadIdx.x;
  const int lane = tid & 63, wave = tid >> 6;
  const int quad = lane >> 4, l16 = lane & 15;
  const int sw = l16 & 7;                            // swizzle key
  const int q0 = qb * 64;

#define STAGE_KV(kbase, bufv) do {                                                 \
    char* kd_ = smem + (bufv) * 16384;                                             \
    char* vd_ = smem + 32768 + (bufv) * 16384;                                     \
    _Pragma("unroll")                                                              \
    for (int pass_ = 0; pass_ < 4; ++pass_) {                                      \
      int c_ = pass_ * 256 + tid;                                                  \
      int row_ = c_ >> 4, ch_ = c_ & 15;                                           \
      int chs_ = ch_ ^ (row_ & 7);                                                 \
      GLD_LDS(&Kr[(size_t)((kbase) + row_) * (NKV * HD) + (size_t)kvh * HD + chs_ * 8], \
              kd_ + c_ * 16);                                                      \
    }                                                                              \
    _Pragma("unroll")                                                              \
    for (int pass_ = 0; pass_ < 4; ++pass_) {                                      \
      int c_ = pass_ * 256 + tid;                                                  \
      int d_ = c_ >> 3, ch_ = c_ & 7;                                              \
      int chs_ = ch_ ^ (d_ & 7);                                                   \
      GLD_LDS(&Vt[((size_t)kvh * HD + d_) * S_LEN + (kbase) + chs_ * 8],           \
              vd_ + c_ * 16);                                                      \
    }                                                                              \
  } while (0)

  bf16x8 qf[4];
  {
    const __bf16* qp = Qr + (size_t)(q0 + wave * 16 + l16) * (NH * HD) + (size_t)h * HD + quad * 8;
    for (int kk = 0; kk < 4; ++kk) qf[kk] = *(const bf16x8*)(qp + kk * 32);
  }
  f32x4 oacc[8] = {};
  float m2 = -INFINITY, l_i = 0.0f;
  const float C2 = SCALE_F * 1.4426950408889634f;

  int buf = 0;
  STAGE_KV(0, 0);
  for (int kb = 0; kb <= q0; kb += 64) {
    __syncthreads();
    if (kb + 64 <= q0) STAGE_KV(kb + 64, buf ^ 1);

    const __bf16* Ks = (const __bf16*)(smem + buf * 16384);
    const __bf16* Vs = (const __bf16*)(smem + 32768 + buf * 16384);

    f32x4 sc[4] = {};
    __builtin_amdgcn_s_setprio(1);
    for (int jt = 0; jt < 4; ++jt)
      for (int kk = 0; kk < 4; ++kk) {
        bf16x8 kf = *(const bf16x8*)&Ks[(jt * 16 + l16) * 128 + ((kk * 4 + quad) ^ sw) * 8];
        sc[jt] = __builtin_amdgcn_mfma_f32_16x16x32_bf16(kf, qf[kk], sc[jt], 0, 0, 0);
      }
    __builtin_amdgcn_s_setprio(0);

    float s[16];
    for (int jt = 0; jt < 4; ++jt)
      for (int r = 0; r < 4; ++r) s[jt * 4 + r] = sc[jt][r];
    if (kb == q0) {
      int qloc = wave * 16 + l16;
      for (int jt = 0; jt < 4; ++jt)
        for (int r = 0; r < 4; ++r)
          if (jt * 16 + quad * 4 + r > qloc) s[jt * 4 + r] = -INFINITY;
    }
    float mx = s[0];
    for (int i = 1; i < 16; ++i) mx = fmaxf(mx, s[i]);
    mx = fmaxf(mx, __shfl_xor(mx, 16, 64));
    mx = fmaxf(mx, __shfl_xor(mx, 32, 64));
    float mxs = mx * C2;
    // T13 defer-max: only rescale when the running max grew by > 11.54 (log2)
    if (!__all(mxs <= m2 + 11.54f)) {
      float m2new = fmaxf(m2, mxs);
      float alpha = exp2f(m2 - m2new);
      l_i *= alpha;
      for (int dt = 0; dt < 8; ++dt) oacc[dt] *= alpha;
      m2 = m2new;
    }
    float pv[16], sum = 0.0f;
    for (int i = 0; i < 16; ++i) { pv[i] = exp2f(fmaf(s[i], C2, -m2)); sum += pv[i]; }
    sum += __shfl_xor(sum, 16, 64);
    sum += __shfl_xor(sum, 32, 64);
    l_i += sum;

    __bf16* pw = Ps + wave * 1024 + l16 * 64;
    for (int jt = 0; jt < 4; ++jt) {
      bf16x4 pk = { (__bf16)pv[jt*4+0], (__bf16)pv[jt*4+1], (__bf16)pv[jt*4+2], (__bf16)pv[jt*4+3] };
      int chunk = jt * 2 + (quad >> 1);
      *(bf16x4*)&pw[((chunk ^ sw) * 8) + (quad & 1) * 4] = pk;
    }
    __builtin_amdgcn_s_setprio(1);
    for (int half = 0; half < 2; ++half) {
      bf16x8 pf = *(const bf16x8*)&pw[((half * 4 + quad) ^ sw) * 8];
      for (int dt = 0; dt < 8; ++dt) {
        bf16x8 vf = *(const bf16x8*)&Vs[(dt * 16 + l16) * 64 + ((half * 4 + quad) ^ sw) * 8];
        oacc[dt] = __builtin_amdgcn_mfma_f32_16x16x32_bf16(vf, pf, oacc[dt], 0, 0, 0);
      }
    }
    __builtin_amdgcn_s_setprio(0);
    buf ^= 1;
  }
  __syncthreads();

#undef STAGE_KV

  float* scr = (float*)smem + wave * 2112;
  float inv = 1.0f / l_i;
  for (int dt = 0; dt < 8; ++dt) {
    f32x4 v = oacc[dt] * inv;
    *(f32x4*)&scr[l16 * 132 + dt * 16 + quad * 4] = v;
  }
  for (int it = 0; it < 4; ++it) {
    int c = it * 64 + lane;
    int row = c >> 4, ch = c & 15;
    const float* sp = &scr[row * 132 + ch * 8];
    f32x4 a = *(const f32x4*)sp;
    f32x4 b = *(const f32x4*)(sp + 4);
    bf16x8 o = { (__bf16)a[0], (__bf16)a[1], (__bf16)a[2], (__bf16)a[3],
                 (__bf16)b[0], (__bf16)b[1], (__bf16)b[2], (__bf16)b[3] };
    *(bf16x8*)&O[(size_t)(q0 + wave * 16 + row) * (NH * HD) + (size_t)h * HD + ch * 8] = o;
  }
}

extern "C" void kernel_launch(void* const* d_in, const int* in_sizes, int n_in,
                              void* d_out, int out_size, void* d_ws, size_t ws_size,
                              hipStream_t stream) {
  const float* hidden    = (const float*)d_in[0];
  const int*   positions = (const int*)d_in[1];
  const float* Wqkv      = (const float*)d_in[2];
  const float* Wo        = (const float*)d_in[3];
  float* out = (float*)d_out;

  char* p = (char*)d_ws;
  auto alloc = [&](size_t bytes) { char* r = p; p += (bytes + 255) & ~(size_t)255; return r; };
  __bf16* hid_bf = (__bf16*)alloc((size_t)S_LEN * HID * 2);       // 16 MB (reused as attn_out)
  __bf16* wqkvT  = (__bf16*)alloc((size_t)QKV_N * HID * 2);       // 48 MB  [6144][4096]
  __bf16* woT    = (__bf16*)alloc((size_t)HID * HID * 2);         // 32 MB  [4096][4096]
  __bf16* qkv    = (__bf16*)alloc((size_t)S_LEN * QKV_N * 2);     // 24 MB
  __bf16* Qr     = (__bf16*)alloc((size_t)S_LEN * NH * HD * 2);   // 16 MB
  __bf16* Kr     = (__bf16*)alloc((size_t)S_LEN * NKV * HD * 2);  // 4 MB
  __bf16* Vt     = (__bf16*)alloc((size_t)S_LEN * NKV * HD * 2);  // 4 MB
  __bf16* attn   = hid_bf;  // hidden_bf16 dead after GEMM1

  // 1: cast + both weight transposes (one launch)
  fused_prep_kernel<<<12288, 256, 0, stream>>>(hidden, hid_bf, Wqkv, wqkvT, Wo, woT);
  // 2: QKV GEMM
  gemm8p_kernel<__bf16><<<dim3(QKV_N / 256, S_LEN / 256, 1), 512, 0, stream>>>(
      hid_bf, wqkvT, qkv, qkv, S_LEN, QKV_N, HID, HID);
  // 3: rope + V transpose (one launch)
  fused_rope_tpv_kernel<<<22528, 256, 0, stream>>>(qkv, positions, Qr, Kr, Vt);
  // 4: attention
  attn_kernel<<<NH * (S_LEN / 64), 256, 0, stream>>>(Qr, Kr, Vt, attn);
  // 5: O-projection (split-K reverted after R5 regression)
  gemm8p_kernel<float><<<dim3(HID / 256, S_LEN / 256, 1), 512, 0, stream>>>(
      attn, woT, out, out, S_LEN, HID, HID, HID);
}